// Round 1
// baseline (547.901 us; speedup 1.0000x reference)
//
#include <hip/hip_runtime.h>
#include <cstdint>
#include <cstddef>

#define HEADS   8
#define NFEAT   256
#define C1      256     // HEADS*NHID
#define NOUT    128
#define NEG     0.2f
#define EPSV    1e-5f

static __device__ __forceinline__ float lrelu(float x) { return x > 0.f ? x : NEG * x; }

// ---------------------------------------------------------------------------
// detect int64 vs int32 edge_index: sample 64 odd 32-bit words; if all zero,
// the buffer is int64 (values < 2^31 => high words are 0).
__global__ void k_detect(const int* __restrict__ ei, int E, int* __restrict__ flag) {
    int i = threadIdx.x;                       // 0..63
    long idx = 2L * ((long)i * (E / 64)) + 1;
    int v = ei[idx];
    unsigned long long ball = __ballot(v == 0);
    if (i == 0) flag[0] = (ball == ~0ull) ? 1 : 0;
}

// ---------------------------------------------------------------------------
// CSR build: count incoming edges per dst (includes self-loops)
__global__ void k_count(const int* __restrict__ ei, const int* __restrict__ flag,
                        int* __restrict__ counts, int E, int n) {
    int i = blockIdx.x * blockDim.x + threadIdx.x;
    int is64 = flag[0];
    if (i < E) {
        int d = ei[(size_t)(E + i) << is64];
        atomicAdd(&counts[d], 1);
    } else if (i < E + n) {
        atomicAdd(&counts[i - E], 1);          // self-loop
    }
}

// 3-phase exclusive scan over counts[n] -> offs[n+1]
__global__ __launch_bounds__(1024) void k_scan1(const int* __restrict__ counts,
                                                int* __restrict__ incl,
                                                int* __restrict__ bsum, int n) {
    int t = threadIdx.x, i = blockIdx.x * 1024 + t;
    int lane = t & 63, w = t >> 6;
    int v = (i < n) ? counts[i] : 0;
    int sv = v;
#pragma unroll
    for (int o = 1; o < 64; o <<= 1) { int u = __shfl_up(sv, o, 64); if (lane >= o) sv += u; }
    __shared__ int wsum[16];
    if (lane == 63) wsum[w] = sv;
    __syncthreads();
    if (w == 0) {
        int bs = (lane < 16) ? wsum[lane] : 0;
#pragma unroll
        for (int o = 1; o < 16; o <<= 1) { int u = __shfl_up(bs, o, 64); if (lane >= o) bs += u; }
        if (lane < 16) wsum[lane] = bs;
    }
    __syncthreads();
    int pre = (w > 0) ? wsum[w - 1] : 0;
    sv += pre;
    if (i < n) incl[i] = sv;
    if (t == 1023) bsum[blockIdx.x] = sv;      // block total (tail lanes added 0)
}

__global__ void k_scan2(int* __restrict__ bsum, int nb) {   // 1 block, 64 thr, nb<=64
    int lane = threadIdx.x;
    int v = (lane < nb) ? bsum[lane] : 0;
    int sv = v;
#pragma unroll
    for (int o = 1; o < 64; o <<= 1) { int u = __shfl_up(sv, o, 64); if (lane >= o) sv += u; }
    if (lane < nb) bsum[lane] = sv - v;        // exclusive
}

__global__ void k_scan3(const int* __restrict__ incl, const int* __restrict__ bsum,
                        int* __restrict__ offs, int* __restrict__ cursor, int n) {
    int i = blockIdx.x * blockDim.x + threadIdx.x;
    if (i < n) {
        int v = incl[i] + bsum[i >> 10];
        offs[i + 1] = v;
    }
    if (i == 0) offs[0] = 0;
}

__global__ void k_cursor(const int* __restrict__ offs, int* __restrict__ cursor, int n) {
    int i = blockIdx.x * blockDim.x + threadIdx.x;
    if (i < n) cursor[i] = offs[i];
}

__global__ void k_fill(const int* __restrict__ ei, const int* __restrict__ flag,
                       int* __restrict__ cursor, int* __restrict__ esrc, int E, int n) {
    int i = blockIdx.x * blockDim.x + threadIdx.x;
    if (i >= E + n) return;
    int is64 = flag[0];
    int s, d;
    if (i < E) { s = ei[(size_t)i << is64]; d = ei[(size_t)(E + i) << is64]; }
    else       { s = i - E; d = s; }
    int p = atomicAdd(&cursor[d], 1);
    esrc[p] = s;
}

// ---------------------------------------------------------------------------
// GEMM: C[n,M] = A[n,256] @ W[256,M]   (64x64 tile, BK=32, 256 threads, 4x4/thr)
template <int M>
__global__ __launch_bounds__(256) void k_gemm(const float* __restrict__ A,
                                              const float* __restrict__ W,
                                              float* __restrict__ C, int n) {
    __shared__ float As[32][64];   // As[kk][row]
    __shared__ float Bs[32][64];   // Bs[kk][col]
    const int r0 = blockIdx.x * 64;
    const int c0 = blockIdx.y * 64;
    const int t = threadIdx.x;
    const int tx = t & 15, ty = t >> 4;
    float acc[4][4] = {};
    for (int kb = 0; kb < 256; kb += 32) {
        {   // A tile (transposed into LDS)
            int ra = t >> 2;
            int kp = (t & 3) * 8;
            int row = r0 + ra;
            float4 v0 = {0, 0, 0, 0}, v1 = {0, 0, 0, 0};
            if (row < n) {
                v0 = *reinterpret_cast<const float4*>(&A[(size_t)row * 256 + kb + kp]);
                v1 = *reinterpret_cast<const float4*>(&A[(size_t)row * 256 + kb + kp + 4]);
            }
            As[kp + 0][ra] = v0.x; As[kp + 1][ra] = v0.y; As[kp + 2][ra] = v0.z; As[kp + 3][ra] = v0.w;
            As[kp + 4][ra] = v1.x; As[kp + 5][ra] = v1.y; As[kp + 6][ra] = v1.z; As[kp + 7][ra] = v1.w;
        }
        {   // B tile
            int kk = t >> 3;
            int cb = (t & 7) * 8;
            const float* wp = &W[(size_t)(kb + kk) * M + c0 + cb];
            float4 b0 = *reinterpret_cast<const float4*>(wp);
            float4 b1 = *reinterpret_cast<const float4*>(wp + 4);
            *reinterpret_cast<float4*>(&Bs[kk][cb]) = b0;
            *reinterpret_cast<float4*>(&Bs[kk][cb + 4]) = b1;
        }
        __syncthreads();
#pragma unroll
        for (int kk = 0; kk < 32; ++kk) {
            float4 a = *reinterpret_cast<const float4*>(&As[kk][ty * 4]);
            float4 b = *reinterpret_cast<const float4*>(&Bs[kk][tx * 4]);
            float av[4] = {a.x, a.y, a.z, a.w};
            float bv[4] = {b.x, b.y, b.z, b.w};
#pragma unroll
            for (int i = 0; i < 4; ++i)
#pragma unroll
                for (int j = 0; j < 4; ++j) acc[i][j] += av[i] * bv[j];
        }
        __syncthreads();
    }
#pragma unroll
    for (int i = 0; i < 4; ++i) {
        int row = r0 + ty * 4 + i;
        if (row < n) {
            float4 o = {acc[i][0], acc[i][1], acc[i][2], acc[i][3]};
            *reinterpret_cast<float4*>(&C[(size_t)row * M + c0 + tx * 4]) = o;
        }
    }
}

// ---------------------------------------------------------------------------
// attention logit dot products, layer 1: one wave per node, 8 heads x 32 ch
__global__ __launch_bounds__(256) void k_att1(const float* __restrict__ h1,
                                              const float* __restrict__ att_s,
                                              const float* __restrict__ att_d,
                                              float* __restrict__ as1,
                                              float* __restrict__ ad1, int n) {
    int wid = (blockIdx.x * blockDim.x + threadIdx.x) >> 6;
    int lane = threadIdx.x & 63;
    if (wid >= n) return;
    int head = lane >> 3;
    int co = (lane & 7) * 4;
    float4 h = *reinterpret_cast<const float4*>(&h1[(size_t)wid * 256 + head * 32 + co]);
    float4 vs = *reinterpret_cast<const float4*>(&att_s[head * 32 + co]);
    float4 vd = *reinterpret_cast<const float4*>(&att_d[head * 32 + co]);
    float ss = h.x * vs.x + h.y * vs.y + h.z * vs.z + h.w * vs.w;
    float sd = h.x * vd.x + h.y * vd.y + h.z * vd.z + h.w * vd.w;
#pragma unroll
    for (int o = 1; o < 8; o <<= 1) { ss += __shfl_xor(ss, o, 64); sd += __shfl_xor(sd, o, 64); }
    if ((lane & 7) == 0) {
        as1[(size_t)wid * 8 + head] = ss;
        ad1[(size_t)wid * 8 + head] = sd;
    }
}

// layer 2: single head over 128 channels
__global__ __launch_bounds__(256) void k_att2(const float* __restrict__ h2,
                                              const float* __restrict__ att_s,
                                              const float* __restrict__ att_d,
                                              float* __restrict__ as2,
                                              float* __restrict__ ad2, int n) {
    int wid = (blockIdx.x * blockDim.x + threadIdx.x) >> 6;
    int lane = threadIdx.x & 63;
    if (wid >= n) return;
    float2 h = *reinterpret_cast<const float2*>(&h2[(size_t)wid * 128 + lane * 2]);
    float2 vs = *reinterpret_cast<const float2*>(&att_s[lane * 2]);
    float2 vd = *reinterpret_cast<const float2*>(&att_d[lane * 2]);
    float ss = h.x * vs.x + h.y * vs.y;
    float sd = h.x * vd.x + h.y * vd.y;
#pragma unroll
    for (int o = 1; o < 64; o <<= 1) { ss += __shfl_xor(ss, o, 64); sd += __shfl_xor(sd, o, 64); }
    if (lane == 0) { as2[wid] = ss; ad2[wid] = sd; }
}

// ---------------------------------------------------------------------------
// layer-1 aggregation: 1 wave/node, online softmax, lane owns 4 channels
__global__ __launch_bounds__(256) void k_agg1(const float* __restrict__ h1,
                                              const float* __restrict__ as1,
                                              const float* __restrict__ ad1,
                                              const int* __restrict__ offs,
                                              const int* __restrict__ esrc,
                                              const float* __restrict__ b1,
                                              float* __restrict__ out1, int n) {
    int wid = (blockIdx.x * blockDim.x + threadIdx.x) >> 6;
    int lane = threadIdx.x & 63;
    if (wid >= n) return;
    int head = lane >> 3;
    int cb = lane * 4;
    float adn = ad1[(size_t)wid * 8 + head];
    int e0 = offs[wid], e1 = offs[wid + 1];
    float m = -1e30f, d = 0.f;
    float ax = 0.f, ay = 0.f, az = 0.f, aw = 0.f;
    for (int e = e0; e < e1; ++e) {
        int s = esrc[e];
        float ea = lrelu(as1[(size_t)s * 8 + head] + adn);
        float nm = fmaxf(m, ea);
        float sc = __expf(m - nm);
        float p = __expf(ea - nm);
        d = d * sc + p;
        float4 hv = *reinterpret_cast<const float4*>(&h1[(size_t)s * 256 + cb]);
        ax = ax * sc + p * hv.x;
        ay = ay * sc + p * hv.y;
        az = az * sc + p * hv.z;
        aw = aw * sc + p * hv.w;
        m = nm;
    }
    float inv = 1.f / (d + 1e-16f);
    float4 bb = *reinterpret_cast<const float4*>(&b1[cb]);
    float4 o;
    o.x = fmaxf(ax * inv + bb.x, 0.f);
    o.y = fmaxf(ay * inv + bb.y, 0.f);
    o.z = fmaxf(az * inv + bb.z, 0.f);
    o.w = fmaxf(aw * inv + bb.w, 0.f);
    *reinterpret_cast<float4*>(&out1[(size_t)wid * 256 + cb]) = o;
}

// layer-2 aggregation: 1 wave/node, lane owns 2 channels
__global__ __launch_bounds__(256) void k_agg2(const float* __restrict__ h2,
                                              const float* __restrict__ as2,
                                              const float* __restrict__ ad2,
                                              const int* __restrict__ offs,
                                              const int* __restrict__ esrc,
                                              const float* __restrict__ b2,
                                              float* __restrict__ out2, int n) {
    int wid = (blockIdx.x * blockDim.x + threadIdx.x) >> 6;
    int lane = threadIdx.x & 63;
    if (wid >= n) return;
    int cb = lane * 2;
    float adn = ad2[wid];
    int e0 = offs[wid], e1 = offs[wid + 1];
    float m = -1e30f, d = 0.f, ax = 0.f, ay = 0.f;
    for (int e = e0; e < e1; ++e) {
        int s = esrc[e];
        float ea = lrelu(as2[s] + adn);
        float nm = fmaxf(m, ea);
        float sc = __expf(m - nm);
        float p = __expf(ea - nm);
        d = d * sc + p;
        float2 hv = *reinterpret_cast<const float2*>(&h2[(size_t)s * 128 + cb]);
        ax = ax * sc + p * hv.x;
        ay = ay * sc + p * hv.y;
        m = nm;
    }
    float inv = 1.f / (d + 1e-16f);
    float o0 = fmaxf(ax * inv + b2[cb], 0.f);
    float o1 = fmaxf(ay * inv + b2[cb + 1], 0.f);
    float2 o = {o0, o1};
    *reinterpret_cast<float2*>(&out2[(size_t)wid * 128 + cb]) = o;
}

// ---------------------------------------------------------------------------
// BatchNorm column stats: per-block register accumulation + 1 atomic/col
__global__ __launch_bounds__(128) void k_bnstat(const float* __restrict__ out2,
                                                float* __restrict__ bnsum,
                                                float* __restrict__ bnsq, int n) {
    int c = threadIdx.x;
    float s = 0.f, q = 0.f;
    for (int r = blockIdx.x; r < n; r += gridDim.x) {
        float v = out2[(size_t)r * 128 + c];
        s += v;
        q += v * v;
    }
    atomicAdd(&bnsum[c], s);
    atomicAdd(&bnsq[c], q);
}

// fused BN (batch stats) + LN over last dim: 1 wave/row
__global__ __launch_bounds__(256) void k_final(const float* __restrict__ out2,
                                               const float* __restrict__ bnsum,
                                               const float* __restrict__ bnsq,
                                               const float* __restrict__ bng,
                                               const float* __restrict__ bnb,
                                               const float* __restrict__ lng,
                                               const float* __restrict__ lnb,
                                               float* __restrict__ out, int n) {
    int wid = (blockIdx.x * blockDim.x + threadIdx.x) >> 6;
    int lane = threadIdx.x & 63;
    if (wid >= n) return;
    int c0 = lane, c1 = lane + 64;
    float invn = 1.f / (float)n;
    float mu0 = bnsum[c0] * invn, mu1 = bnsum[c1] * invn;
    float v0 = bnsq[c0] * invn - mu0 * mu0;
    float v1 = bnsq[c1] * invn - mu1 * mu1;
    float r0 = rsqrtf(v0 + EPSV), r1 = rsqrtf(v1 + EPSV);
    float x0 = out2[(size_t)wid * 128 + c0];
    float x1 = out2[(size_t)wid * 128 + c1];
    float y0 = (x0 - mu0) * r0 * bng[c0] + bnb[c0];
    float y1 = (x1 - mu1) * r1 * bng[c1] + bnb[c1];
    float s = y0 + y1, q = y0 * y0 + y1 * y1;
#pragma unroll
    for (int o = 1; o < 64; o <<= 1) { s += __shfl_xor(s, o, 64); q += __shfl_xor(q, o, 64); }
    float mu = s * (1.f / 128.f);
    float var = q * (1.f / 128.f) - mu * mu;
    float rr = rsqrtf(var + EPSV);
    out[(size_t)wid * 128 + c0] = (y0 - mu) * rr * lng[c0] + lnb[c0];
    out[(size_t)wid * 128 + c1] = (y1 - mu) * rr * lng[c1] + lnb[c1];
}

// ---------------------------------------------------------------------------
extern "C" void kernel_launch(void* const* d_in, const int* in_sizes, int n_in,
                              void* d_out, int out_size, void* d_ws, size_t ws_size,
                              hipStream_t stream) {
    const float* x    = (const float*)d_in[0];
    const int*   ei   = (const int*)d_in[1];
    const float* W1   = (const float*)d_in[2];
    const float* ats1 = (const float*)d_in[3];
    const float* atd1 = (const float*)d_in[4];
    const float* b1   = (const float*)d_in[5];
    const float* W2   = (const float*)d_in[6];
    const float* ats2 = (const float*)d_in[7];
    const float* atd2 = (const float*)d_in[8];
    const float* b2   = (const float*)d_in[9];
    const float* bng  = (const float*)d_in[10];
    const float* bnb  = (const float*)d_in[11];
    const float* lng  = (const float*)d_in[12];
    const float* lnb  = (const float*)d_in[13];

    const int n = in_sizes[0] / NFEAT;   // 50000
    const int E = in_sizes[1] / 2;       // 800000
    const int tot = E + n;

    auto align = [](size_t v) { return (v + 255) & ~(size_t)255; };
    char* ws = (char*)d_ws;
    size_t off = 0;
    float* h1   = (float*)(ws + off); off += align((size_t)n * 256 * 4);
    float* out1 = (float*)(ws + off); off += align((size_t)n * 256 * 4);
    float* h2   = h1;     // h1 dead after k_agg1
    float* out2 = out1;   // out1 dead after k_gemm<128>
    float* as1 = (float*)(ws + off); off += align((size_t)n * 8 * 4);
    float* ad1 = (float*)(ws + off); off += align((size_t)n * 8 * 4);
    float* as2 = (float*)(ws + off); off += align((size_t)n * 4);
    float* ad2 = (float*)(ws + off); off += align((size_t)n * 4);
    int* counts = (int*)(ws + off); off += align((size_t)n * 4);
    int* offs   = (int*)(ws + off); off += align((size_t)(n + 1) * 4);
    int* cursor = (int*)(ws + off); off += align((size_t)n * 4);
    int* esrc   = (int*)(ws + off); off += align((size_t)tot * 4);
    int* incl   = (int*)(ws + off); off += align((size_t)n * 4);
    int* bsum   = (int*)(ws + off); off += align(64 * 4);
    int* flag   = (int*)(ws + off); off += align(4);
    float* bnsum = (float*)(ws + off); off += align(128 * 4);
    float* bnsq  = (float*)(ws + off); off += align(128 * 4);

    hipMemsetAsync(counts, 0, (size_t)n * 4, stream);
    hipMemsetAsync(bnsum, 0, 128 * 4, stream);
    hipMemsetAsync(bnsq, 0, 128 * 4, stream);

    // edge dtype detection + CSR build
    k_detect<<<1, 64, 0, stream>>>(ei, E, flag);
    k_count<<<(tot + 255) / 256, 256, 0, stream>>>(ei, flag, counts, E, n);
    int nsb = (n + 1023) / 1024;
    k_scan1<<<nsb, 1024, 0, stream>>>(counts, incl, bsum, n);
    k_scan2<<<1, 64, 0, stream>>>(bsum, nsb);
    k_scan3<<<(n + 255) / 256, 256, 0, stream>>>(incl, bsum, offs, cursor, n);
    k_cursor<<<(n + 255) / 256, 256, 0, stream>>>(offs, cursor, n);
    k_fill<<<(tot + 255) / 256, 256, 0, stream>>>(ei, flag, cursor, esrc, E, n);

    // layer 1
    k_gemm<256><<<dim3((n + 63) / 64, 4), 256, 0, stream>>>(x, W1, h1, n);
    k_att1<<<(n + 3) / 4, 256, 0, stream>>>(h1, ats1, atd1, as1, ad1, n);
    k_agg1<<<(n + 3) / 4, 256, 0, stream>>>(h1, as1, ad1, offs, esrc, b1, out1, n);

    // layer 2
    k_gemm<128><<<dim3((n + 63) / 64, 2), 256, 0, stream>>>(out1, W2, h2, n);
    k_att2<<<(n + 3) / 4, 256, 0, stream>>>(h2, ats2, atd2, as2, ad2, n);
    k_agg2<<<(n + 3) / 4, 256, 0, stream>>>(h2, as2, ad2, offs, esrc, b2, out2, n);

    // BN (batch stats) + LN
    k_bnstat<<<512, 128, 0, stream>>>(out2, bnsum, bnsq, n);
    k_final<<<(n + 3) / 4, 256, 0, stream>>>(out2, bnsum, bnsq, bng, bnb, lng, lnb,
                                             (float*)d_out, n);
}

// Round 2
// 449.861 us; speedup vs baseline: 1.2179x; 1.2179x over previous
//
#include <hip/hip_runtime.h>
#include <cstdint>
#include <cstddef>

#define HEADS   8
#define NFEAT   256
#define C1      256     // HEADS*NHID
#define NOUT    128
#define NEG     0.2f
#define EPSV    1e-5f

static __device__ __forceinline__ float lrelu(float x) { return x > 0.f ? x : NEG * x; }

static __device__ __forceinline__ float bf2f(unsigned short u) {
    union { unsigned int i; float f; } v; v.i = ((unsigned int)u) << 16; return v.f;
}
static __device__ __forceinline__ unsigned short f2bf(float f) {
    union { float f; unsigned int i; } v; v.f = f;
    unsigned int x = v.i;
    return (unsigned short)((x + 0x7fff + ((x >> 16) & 1)) >> 16);   // RNE
}

// ---------------------------------------------------------------------------
// detect int64 vs int32 edge_index: sample 64 odd 32-bit words; if all zero,
// the buffer is int64 (values < 2^31 => high words are 0).
__global__ void k_detect(const int* __restrict__ ei, int E, int* __restrict__ flag) {
    int i = threadIdx.x;                       // 0..63
    long idx = 2L * ((long)i * (E / 64)) + 1;
    int v = ei[idx];
    unsigned long long ball = __ballot(v == 0);
    if (i == 0) flag[0] = (ball == ~0ull) ? 1 : 0;
}

// ---------------------------------------------------------------------------
// CSR build: count incoming edges per dst (includes self-loops)
__global__ void k_count(const int* __restrict__ ei, const int* __restrict__ flag,
                        int* __restrict__ counts, int E, int n) {
    int i = blockIdx.x * blockDim.x + threadIdx.x;
    int is64 = flag[0];
    if (i < E) {
        int d = ei[(size_t)(E + i) << is64];
        atomicAdd(&counts[d], 1);
    } else if (i < E + n) {
        atomicAdd(&counts[i - E], 1);          // self-loop
    }
}

// 3-phase exclusive scan over counts[n] -> offs[n+1]
__global__ __launch_bounds__(1024) void k_scan1(const int* __restrict__ counts,
                                                int* __restrict__ incl,
                                                int* __restrict__ bsum, int n) {
    int t = threadIdx.x, i = blockIdx.x * 1024 + t;
    int lane = t & 63, w = t >> 6;
    int v = (i < n) ? counts[i] : 0;
    int sv = v;
#pragma unroll
    for (int o = 1; o < 64; o <<= 1) { int u = __shfl_up(sv, o, 64); if (lane >= o) sv += u; }
    __shared__ int wsum[16];
    if (lane == 63) wsum[w] = sv;
    __syncthreads();
    if (w == 0) {
        int bs = (lane < 16) ? wsum[lane] : 0;
#pragma unroll
        for (int o = 1; o < 16; o <<= 1) { int u = __shfl_up(bs, o, 64); if (lane >= o) bs += u; }
        if (lane < 16) wsum[lane] = bs;
    }
    __syncthreads();
    int pre = (w > 0) ? wsum[w - 1] : 0;
    sv += pre;
    if (i < n) incl[i] = sv;
    if (t == 1023) bsum[blockIdx.x] = sv;      // block total (tail lanes added 0)
}

__global__ void k_scan2(int* __restrict__ bsum, int nb) {   // 1 block, 64 thr, nb<=64
    int lane = threadIdx.x;
    int v = (lane < nb) ? bsum[lane] : 0;
    int sv = v;
#pragma unroll
    for (int o = 1; o < 64; o <<= 1) { int u = __shfl_up(sv, o, 64); if (lane >= o) sv += u; }
    if (lane < nb) bsum[lane] = sv - v;        // exclusive
}

__global__ void k_scan3(const int* __restrict__ incl, const int* __restrict__ bsum,
                        const int* __restrict__ counts,
                        int* __restrict__ offs, int* __restrict__ cursor, int n) {
    int i = blockIdx.x * blockDim.x + threadIdx.x;
    if (i < n) {
        int v = incl[i] + bsum[i >> 10];
        offs[i + 1] = v;
        cursor[i] = v - counts[i];
    }
    if (i == 0) offs[0] = 0;
}

__global__ void k_fill(const int* __restrict__ ei, const int* __restrict__ flag,
                       int* __restrict__ cursor, int* __restrict__ esrc, int E, int n) {
    int i = blockIdx.x * blockDim.x + threadIdx.x;
    if (i >= E + n) return;
    int is64 = flag[0];
    int s, d;
    if (i < E) { s = ei[(size_t)i << is64]; d = ei[(size_t)(E + i) << is64]; }
    else       { s = i - E; d = s; }
    int p = atomicAdd(&cursor[d], 1);
    esrc[p] = s;
}

// ---------------------------------------------------------------------------
// GEMM: C[n,M] = A[n,256] @ W[256,M], bf16 output
// (64x64 tile, BK=32, 256 threads, 4x4/thr)
template <int M>
__global__ __launch_bounds__(256) void k_gemm(const float* __restrict__ A,
                                              const float* __restrict__ W,
                                              unsigned short* __restrict__ Cb, int n) {
    __shared__ float As[32][64];   // As[kk][row]
    __shared__ float Bs[32][64];   // Bs[kk][col]
    const int r0 = blockIdx.x * 64;
    const int c0 = blockIdx.y * 64;
    const int t = threadIdx.x;
    const int tx = t & 15, ty = t >> 4;
    float acc[4][4] = {};
    for (int kb = 0; kb < 256; kb += 32) {
        {   // A tile (transposed into LDS)
            int ra = t >> 2;
            int kp = (t & 3) * 8;
            int row = r0 + ra;
            float4 v0 = {0, 0, 0, 0}, v1 = {0, 0, 0, 0};
            if (row < n) {
                v0 = *reinterpret_cast<const float4*>(&A[(size_t)row * 256 + kb + kp]);
                v1 = *reinterpret_cast<const float4*>(&A[(size_t)row * 256 + kb + kp + 4]);
            }
            As[kp + 0][ra] = v0.x; As[kp + 1][ra] = v0.y; As[kp + 2][ra] = v0.z; As[kp + 3][ra] = v0.w;
            As[kp + 4][ra] = v1.x; As[kp + 5][ra] = v1.y; As[kp + 6][ra] = v1.z; As[kp + 7][ra] = v1.w;
        }
        {   // B tile
            int kk = t >> 3;
            int cb = (t & 7) * 8;
            const float* wp = &W[(size_t)(kb + kk) * M + c0 + cb];
            float4 b0 = *reinterpret_cast<const float4*>(wp);
            float4 b1 = *reinterpret_cast<const float4*>(wp + 4);
            *reinterpret_cast<float4*>(&Bs[kk][cb]) = b0;
            *reinterpret_cast<float4*>(&Bs[kk][cb + 4]) = b1;
        }
        __syncthreads();
#pragma unroll
        for (int kk = 0; kk < 32; ++kk) {
            float4 a = *reinterpret_cast<const float4*>(&As[kk][ty * 4]);
            float4 b = *reinterpret_cast<const float4*>(&Bs[kk][tx * 4]);
            float av[4] = {a.x, a.y, a.z, a.w};
            float bv[4] = {b.x, b.y, b.z, b.w};
#pragma unroll
            for (int i = 0; i < 4; ++i)
#pragma unroll
                for (int j = 0; j < 4; ++j) acc[i][j] += av[i] * bv[j];
        }
        __syncthreads();
    }
#pragma unroll
    for (int i = 0; i < 4; ++i) {
        int row = r0 + ty * 4 + i;
        if (row < n) {
            ushort4 o;
            o.x = f2bf(acc[i][0]); o.y = f2bf(acc[i][1]);
            o.z = f2bf(acc[i][2]); o.w = f2bf(acc[i][3]);
            *reinterpret_cast<ushort4*>(&Cb[(size_t)row * M + c0 + tx * 4]) = o;
        }
    }
}

// ---------------------------------------------------------------------------
// attention logit dot products, layer 1: one wave per node, 8 heads x 32 ch
__global__ __launch_bounds__(256) void k_att1(const unsigned short* __restrict__ h1,
                                              const float* __restrict__ att_s,
                                              const float* __restrict__ att_d,
                                              float* __restrict__ as1,
                                              float* __restrict__ ad1, int n) {
    int wid = (blockIdx.x * blockDim.x + threadIdx.x) >> 6;
    int lane = threadIdx.x & 63;
    if (wid >= n) return;
    int head = lane >> 3;
    int co = (lane & 7) * 4;
    ushort4 hu = *reinterpret_cast<const ushort4*>(&h1[(size_t)wid * 256 + head * 32 + co]);
    float4 vs = *reinterpret_cast<const float4*>(&att_s[head * 32 + co]);
    float4 vd = *reinterpret_cast<const float4*>(&att_d[head * 32 + co]);
    float hx = bf2f(hu.x), hy = bf2f(hu.y), hz = bf2f(hu.z), hw = bf2f(hu.w);
    float ss = hx * vs.x + hy * vs.y + hz * vs.z + hw * vs.w;
    float sd = hx * vd.x + hy * vd.y + hz * vd.z + hw * vd.w;
#pragma unroll
    for (int o = 1; o < 8; o <<= 1) { ss += __shfl_xor(ss, o, 64); sd += __shfl_xor(sd, o, 64); }
    if ((lane & 7) == 0) {
        as1[(size_t)wid * 8 + head] = ss;
        ad1[(size_t)wid * 8 + head] = sd;
    }
}

// layer 2: single head over 128 channels
__global__ __launch_bounds__(256) void k_att2(const unsigned short* __restrict__ h2,
                                              const float* __restrict__ att_s,
                                              const float* __restrict__ att_d,
                                              float* __restrict__ as2,
                                              float* __restrict__ ad2, int n) {
    int wid = (blockIdx.x * blockDim.x + threadIdx.x) >> 6;
    int lane = threadIdx.x & 63;
    if (wid >= n) return;
    ushort2 hu = *reinterpret_cast<const ushort2*>(&h2[(size_t)wid * 128 + lane * 2]);
    float2 vs = *reinterpret_cast<const float2*>(&att_s[lane * 2]);
    float2 vd = *reinterpret_cast<const float2*>(&att_d[lane * 2]);
    float hx = bf2f(hu.x), hy = bf2f(hu.y);
    float ss = hx * vs.x + hy * vs.y;
    float sd = hx * vd.x + hy * vd.y;
#pragma unroll
    for (int o = 1; o < 64; o <<= 1) { ss += __shfl_xor(ss, o, 64); sd += __shfl_xor(sd, o, 64); }
    if (lane == 0) { as2[wid] = ss; ad2[wid] = sd; }
}

// ---------------------------------------------------------------------------
// layer-1 aggregation: 1 wave/node, dual online-softmax accumulators (even/odd
// edges) to halve the serial dependence chain and double MLP. Lane owns 4 ch.
__global__ __launch_bounds__(256) void k_agg1(const unsigned short* __restrict__ h1,
                                              const float* __restrict__ as1,
                                              const float* __restrict__ ad1,
                                              const int* __restrict__ offs,
                                              const int* __restrict__ esrc,
                                              const float* __restrict__ b1,
                                              float* __restrict__ out1, int n) {
    int wid = (blockIdx.x * blockDim.x + threadIdx.x) >> 6;
    int lane = threadIdx.x & 63;
    if (wid >= n) return;
    int head = lane >> 3;
    int cb = lane * 4;
    float adn = ad1[(size_t)wid * 8 + head];
    int e0 = offs[wid], e1 = offs[wid + 1];
    float mA = -1e30f, dA = 0.f, axA = 0.f, ayA = 0.f, azA = 0.f, awA = 0.f;
    float mB = -1e30f, dB = 0.f, axB = 0.f, ayB = 0.f, azB = 0.f, awB = 0.f;
    int e = e0;
    for (; e + 1 < e1; e += 2) {
        int sA = esrc[e], sB = esrc[e + 1];
        float eaA = lrelu(as1[(size_t)sA * 8 + head] + adn);
        float eaB = lrelu(as1[(size_t)sB * 8 + head] + adn);
        ushort4 hA = *reinterpret_cast<const ushort4*>(&h1[(size_t)sA * 256 + cb]);
        ushort4 hB = *reinterpret_cast<const ushort4*>(&h1[(size_t)sB * 256 + cb]);
        float nmA = fmaxf(mA, eaA), nmB = fmaxf(mB, eaB);
        float scA = __expf(mA - nmA), scB = __expf(mB - nmB);
        float pA = __expf(eaA - nmA), pB = __expf(eaB - nmB);
        dA = dA * scA + pA;             dB = dB * scB + pB;
        axA = axA * scA + pA * bf2f(hA.x);  axB = axB * scB + pB * bf2f(hB.x);
        ayA = ayA * scA + pA * bf2f(hA.y);  ayB = ayB * scB + pB * bf2f(hB.y);
        azA = azA * scA + pA * bf2f(hA.z);  azB = azB * scB + pB * bf2f(hB.z);
        awA = awA * scA + pA * bf2f(hA.w);  awB = awB * scB + pB * bf2f(hB.w);
        mA = nmA; mB = nmB;
    }
    if (e < e1) {
        int s = esrc[e];
        float ea = lrelu(as1[(size_t)s * 8 + head] + adn);
        ushort4 hv = *reinterpret_cast<const ushort4*>(&h1[(size_t)s * 256 + cb]);
        float nm = fmaxf(mA, ea);
        float sc = __expf(mA - nm), p = __expf(ea - nm);
        dA = dA * sc + p;
        axA = axA * sc + p * bf2f(hv.x);
        ayA = ayA * sc + p * bf2f(hv.y);
        azA = azA * sc + p * bf2f(hv.z);
        awA = awA * sc + p * bf2f(hv.w);
        mA = nm;
    }
    // merge B into A
    {
        float nm = fmaxf(mA, mB);
        float scA = __expf(mA - nm), scB = __expf(mB - nm);
        dA = dA * scA + dB * scB;
        axA = axA * scA + axB * scB;
        ayA = ayA * scA + ayB * scB;
        azA = azA * scA + azB * scB;
        awA = awA * scA + awB * scB;
    }
    float inv = 1.f / (dA + 1e-16f);
    float4 bb = *reinterpret_cast<const float4*>(&b1[cb]);
    float4 o;
    o.x = fmaxf(axA * inv + bb.x, 0.f);
    o.y = fmaxf(ayA * inv + bb.y, 0.f);
    o.z = fmaxf(azA * inv + bb.z, 0.f);
    o.w = fmaxf(awA * inv + bb.w, 0.f);
    *reinterpret_cast<float4*>(&out1[(size_t)wid * 256 + cb]) = o;
}

// layer-2 aggregation: 1 wave/node, dual accumulators, lane owns 2 channels
__global__ __launch_bounds__(256) void k_agg2(const unsigned short* __restrict__ h2,
                                              const float* __restrict__ as2,
                                              const float* __restrict__ ad2,
                                              const int* __restrict__ offs,
                                              const int* __restrict__ esrc,
                                              const float* __restrict__ b2,
                                              float* __restrict__ out2, int n) {
    int wid = (blockIdx.x * blockDim.x + threadIdx.x) >> 6;
    int lane = threadIdx.x & 63;
    if (wid >= n) return;
    int cb = lane * 2;
    float adn = ad2[wid];
    int e0 = offs[wid], e1 = offs[wid + 1];
    float mA = -1e30f, dA = 0.f, axA = 0.f, ayA = 0.f;
    float mB = -1e30f, dB = 0.f, axB = 0.f, ayB = 0.f;
    int e = e0;
    for (; e + 1 < e1; e += 2) {
        int sA = esrc[e], sB = esrc[e + 1];
        float eaA = lrelu(as2[sA] + adn);
        float eaB = lrelu(as2[sB] + adn);
        ushort2 hA = *reinterpret_cast<const ushort2*>(&h2[(size_t)sA * 128 + cb]);
        ushort2 hB = *reinterpret_cast<const ushort2*>(&h2[(size_t)sB * 128 + cb]);
        float nmA = fmaxf(mA, eaA), nmB = fmaxf(mB, eaB);
        float scA = __expf(mA - nmA), scB = __expf(mB - nmB);
        float pA = __expf(eaA - nmA), pB = __expf(eaB - nmB);
        dA = dA * scA + pA;                 dB = dB * scB + pB;
        axA = axA * scA + pA * bf2f(hA.x); axB = axB * scB + pB * bf2f(hB.x);
        ayA = ayA * scA + pA * bf2f(hA.y); ayB = ayB * scB + pB * bf2f(hB.y);
        mA = nmA; mB = nmB;
    }
    if (e < e1) {
        int s = esrc[e];
        float ea = lrelu(as2[s] + adn);
        ushort2 hv = *reinterpret_cast<const ushort2*>(&h2[(size_t)s * 128 + cb]);
        float nm = fmaxf(mA, ea);
        float sc = __expf(mA - nm), p = __expf(ea - nm);
        dA = dA * sc + p;
        axA = axA * sc + p * bf2f(hv.x);
        ayA = ayA * sc + p * bf2f(hv.y);
        mA = nm;
    }
    {
        float nm = fmaxf(mA, mB);
        float scA = __expf(mA - nm), scB = __expf(mB - nm);
        dA = dA * scA + dB * scB;
        axA = axA * scA + axB * scB;
        ayA = ayA * scA + ayB * scB;
    }
    float inv = 1.f / (dA + 1e-16f);
    float o0 = fmaxf(axA * inv + b2[cb], 0.f);
    float o1 = fmaxf(ayA * inv + b2[cb + 1], 0.f);
    float2 o = {o0, o1};
    *reinterpret_cast<float2*>(&out2[(size_t)wid * 128 + cb]) = o;
}

// ---------------------------------------------------------------------------
// BatchNorm column stats: per-block register accumulation + 1 atomic/col
__global__ __launch_bounds__(128) void k_bnstat(const float* __restrict__ out2,
                                                float* __restrict__ bnsum,
                                                float* __restrict__ bnsq, int n) {
    int c = threadIdx.x;
    float s = 0.f, q = 0.f;
    for (int r = blockIdx.x; r < n; r += gridDim.x) {
        float v = out2[(size_t)r * 128 + c];
        s += v;
        q += v * v;
    }
    atomicAdd(&bnsum[c], s);
    atomicAdd(&bnsq[c], q);
}

// fused BN (batch stats) + LN over last dim: 1 wave/row
__global__ __launch_bounds__(256) void k_final(const float* __restrict__ out2,
                                               const float* __restrict__ bnsum,
                                               const float* __restrict__ bnsq,
                                               const float* __restrict__ bng,
                                               const float* __restrict__ bnb,
                                               const float* __restrict__ lng,
                                               const float* __restrict__ lnb,
                                               float* __restrict__ out, int n) {
    int wid = (blockIdx.x * blockDim.x + threadIdx.x) >> 6;
    int lane = threadIdx.x & 63;
    if (wid >= n) return;
    int c0 = lane, c1 = lane + 64;
    float invn = 1.f / (float)n;
    float mu0 = bnsum[c0] * invn, mu1 = bnsum[c1] * invn;
    float v0 = bnsq[c0] * invn - mu0 * mu0;
    float v1 = bnsq[c1] * invn - mu1 * mu1;
    float r0 = rsqrtf(v0 + EPSV), r1 = rsqrtf(v1 + EPSV);
    float x0 = out2[(size_t)wid * 128 + c0];
    float x1 = out2[(size_t)wid * 128 + c1];
    float y0 = (x0 - mu0) * r0 * bng[c0] + bnb[c0];
    float y1 = (x1 - mu1) * r1 * bng[c1] + bnb[c1];
    float s = y0 + y1, q = y0 * y0 + y1 * y1;
#pragma unroll
    for (int o = 1; o < 64; o <<= 1) { s += __shfl_xor(s, o, 64); q += __shfl_xor(q, o, 64); }
    float mu = s * (1.f / 128.f);
    float var = q * (1.f / 128.f) - mu * mu;
    float rr = rsqrtf(var + EPSV);
    out[(size_t)wid * 128 + c0] = (y0 - mu) * rr * lng[c0] + lnb[c0];
    out[(size_t)wid * 128 + c1] = (y1 - mu) * rr * lng[c1] + lnb[c1];
}

// ---------------------------------------------------------------------------
extern "C" void kernel_launch(void* const* d_in, const int* in_sizes, int n_in,
                              void* d_out, int out_size, void* d_ws, size_t ws_size,
                              hipStream_t stream) {
    const float* x    = (const float*)d_in[0];
    const int*   ei   = (const int*)d_in[1];
    const float* W1   = (const float*)d_in[2];
    const float* ats1 = (const float*)d_in[3];
    const float* atd1 = (const float*)d_in[4];
    const float* b1   = (const float*)d_in[5];
    const float* W2   = (const float*)d_in[6];
    const float* ats2 = (const float*)d_in[7];
    const float* atd2 = (const float*)d_in[8];
    const float* b2   = (const float*)d_in[9];
    const float* bng  = (const float*)d_in[10];
    const float* bnb  = (const float*)d_in[11];
    const float* lng  = (const float*)d_in[12];
    const float* lnb  = (const float*)d_in[13];

    const int n = in_sizes[0] / NFEAT;   // 50000
    const int E = in_sizes[1] / 2;       // 800000
    const int tot = E + n;

    auto align = [](size_t v) { return (v + 255) & ~(size_t)255; };
    char* ws = (char*)d_ws;
    size_t off = 0;
    unsigned short* h1 = (unsigned short*)(ws + off); off += align((size_t)n * 256 * 2);
    float* out1 = (float*)(ws + off); off += align((size_t)n * 256 * 4);
    unsigned short* h2 = h1;   // h1 dead after k_agg1; n*128*2 fits
    float* out2 = out1;        // out1 dead after k_gemm<128>
    float* as1 = (float*)(ws + off); off += align((size_t)n * 8 * 4);
    float* ad1 = (float*)(ws + off); off += align((size_t)n * 8 * 4);
    float* as2 = (float*)(ws + off); off += align((size_t)n * 4);
    float* ad2 = (float*)(ws + off); off += align((size_t)n * 4);
    int* counts = (int*)(ws + off); off += align((size_t)n * 4);
    int* offs   = (int*)(ws + off); off += align((size_t)(n + 1) * 4);
    int* cursor = (int*)(ws + off); off += align((size_t)n * 4);
    int* esrc   = (int*)(ws + off); off += align((size_t)tot * 4);
    int* incl   = (int*)(ws + off); off += align((size_t)n * 4);
    int* bsum   = (int*)(ws + off); off += align(64 * 4);
    int* flag   = (int*)(ws + off); off += align(4);
    float* bnsum = (float*)(ws + off); off += align(128 * 4);
    float* bnsq  = (float*)(ws + off); off += align(128 * 4);

    hipMemsetAsync(counts, 0, (size_t)n * 4, stream);
    hipMemsetAsync(bnsum, 0, 128 * 4, stream);
    hipMemsetAsync(bnsq, 0, 128 * 4, stream);

    // edge dtype detection + CSR build
    k_detect<<<1, 64, 0, stream>>>(ei, E, flag);
    k_count<<<(tot + 255) / 256, 256, 0, stream>>>(ei, flag, counts, E, n);
    int nsb = (n + 1023) / 1024;
    k_scan1<<<nsb, 1024, 0, stream>>>(counts, incl, bsum, n);
    k_scan2<<<1, 64, 0, stream>>>(bsum, nsb);
    k_scan3<<<(n + 255) / 256, 256, 0, stream>>>(incl, bsum, counts, offs, cursor, n);
    k_fill<<<(tot + 255) / 256, 256, 0, stream>>>(ei, flag, cursor, esrc, E, n);

    // layer 1
    k_gemm<256><<<dim3((n + 63) / 64, 4), 256, 0, stream>>>(x, W1, h1, n);
    k_att1<<<(n + 3) / 4, 256, 0, stream>>>(h1, ats1, atd1, as1, ad1, n);
    k_agg1<<<(n + 3) / 4, 256, 0, stream>>>(h1, as1, ad1, offs, esrc, b1, out1, n);

    // layer 2
    k_gemm<128><<<dim3((n + 63) / 64, 2), 256, 0, stream>>>(out1, W2, h2, n);
    k_att2<<<(n + 3) / 4, 256, 0, stream>>>(h2, ats2, atd2, as2, ad2, n);
    k_agg2<<<(n + 3) / 4, 256, 0, stream>>>(h2, as2, ad2, offs, esrc, b2, out2, n);

    // BN (batch stats) + LN
    k_bnstat<<<512, 128, 0, stream>>>(out2, bnsum, bnsq, n);
    k_final<<<(n + 3) / 4, 256, 0, stream>>>(out2, bnsum, bnsq, bng, bnb, lng, lnb,
                                             (float*)d_out, n);
}

// Round 3
// 397.758 us; speedup vs baseline: 1.3775x; 1.1310x over previous
//
#include <hip/hip_runtime.h>
#include <cstdint>
#include <cstddef>

#define HEADS   8
#define NFEAT   256
#define NOUT    128
#define NEG     0.2f
#define EPSV    1e-5f

typedef unsigned short ushort_t;
typedef __attribute__((ext_vector_type(8))) short s8v;   // 8 bf16 = 4 VGPR
typedef __attribute__((ext_vector_type(4))) float f4v;   // MFMA accum

static __device__ __forceinline__ float lrelu(float x) { return x > 0.f ? x : NEG * x; }

static __device__ __forceinline__ float bf2f(ushort_t u) {
    union { unsigned int i; float f; } v; v.i = ((unsigned int)u) << 16; return v.f;
}
static __device__ __forceinline__ ushort_t f2bf(float f) {
    union { float f; unsigned int i; } v; v.f = f;
    unsigned int x = v.i;
    return (ushort_t)((x + 0x7fff + ((x >> 16) & 1)) >> 16);   // RNE
}

// ---------------------------------------------------------------------------
// detect int64 vs int32 edge_index
__global__ void k_detect(const int* __restrict__ ei, int E, int* __restrict__ flag) {
    int i = threadIdx.x;
    long idx = 2L * ((long)i * (E / 64)) + 1;
    int v = ei[idx];
    unsigned long long ball = __ballot(v == 0);
    if (i == 0) flag[0] = (ball == ~0ull) ? 1 : 0;
}

// ---------------------------------------------------------------------------
// CSR build
__global__ void k_count(const int* __restrict__ ei, const int* __restrict__ flag,
                        int* __restrict__ counts, int E, int n) {
    int i = blockIdx.x * blockDim.x + threadIdx.x;
    int is64 = flag[0];
    if (i < E) {
        int d = ei[(size_t)(E + i) << is64];
        atomicAdd(&counts[d], 1);
    } else if (i < E + n) {
        atomicAdd(&counts[i - E], 1);
    }
}

__global__ __launch_bounds__(1024) void k_scan1(const int* __restrict__ counts,
                                                int* __restrict__ incl,
                                                int* __restrict__ bsum, int n) {
    int t = threadIdx.x, i = blockIdx.x * 1024 + t;
    int lane = t & 63, w = t >> 6;
    int v = (i < n) ? counts[i] : 0;
    int sv = v;
#pragma unroll
    for (int o = 1; o < 64; o <<= 1) { int u = __shfl_up(sv, o, 64); if (lane >= o) sv += u; }
    __shared__ int wsum[16];
    if (lane == 63) wsum[w] = sv;
    __syncthreads();
    if (w == 0) {
        int bs = (lane < 16) ? wsum[lane] : 0;
#pragma unroll
        for (int o = 1; o < 16; o <<= 1) { int u = __shfl_up(bs, o, 64); if (lane >= o) bs += u; }
        if (lane < 16) wsum[lane] = bs;
    }
    __syncthreads();
    int pre = (w > 0) ? wsum[w - 1] : 0;
    sv += pre;
    if (i < n) incl[i] = sv;
    if (t == 1023) bsum[blockIdx.x] = sv;
}

__global__ void k_scan2(int* __restrict__ bsum, int nb) {
    int lane = threadIdx.x;
    int v = (lane < nb) ? bsum[lane] : 0;
    int sv = v;
#pragma unroll
    for (int o = 1; o < 64; o <<= 1) { int u = __shfl_up(sv, o, 64); if (lane >= o) sv += u; }
    if (lane < nb) bsum[lane] = sv - v;
}

__global__ void k_scan3(const int* __restrict__ incl, const int* __restrict__ bsum,
                        const int* __restrict__ counts,
                        int* __restrict__ offs, int* __restrict__ cursor, int n) {
    int i = blockIdx.x * blockDim.x + threadIdx.x;
    if (i < n) {
        int v = incl[i] + bsum[i >> 10];
        offs[i + 1] = v;
        cursor[i] = v - counts[i];
    }
    if (i == 0) offs[0] = 0;
}

__global__ void k_fill(const int* __restrict__ ei, const int* __restrict__ flag,
                       int* __restrict__ cursor, int* __restrict__ esrc, int E, int n) {
    int i = blockIdx.x * blockDim.x + threadIdx.x;
    if (i >= E + n) return;
    int is64 = flag[0];
    int s, d;
    if (i < E) { s = ei[(size_t)i << is64]; d = ei[(size_t)(E + i) << is64]; }
    else       { s = i - E; d = s; }
    int p = atomicAdd(&cursor[d], 1);
    esrc[p] = s;
}

// ---------------------------------------------------------------------------
// pack W[K,M] f32 -> hi/lo bf16 in per-lane B-fragment order:
// p = ((ntile*(K/8) + kc)*16 + j)*8 + e  with k = kc*8+e, col = ntile*16+j
__global__ void k_prepw(const float* __restrict__ W, ushort_t* __restrict__ Wh,
                        ushort_t* __restrict__ Wl, int K, int M) {
    int gid = blockIdx.x * 256 + threadIdx.x;
    if (gid >= K * M) return;
    int k = gid / M, nn = gid - k * M;
    int ntile = nn >> 4, j = nn & 15, kc = k >> 3, e = k & 7;
    int p = ((ntile * (K >> 3) + kc) * 16 + j) * 8 + e;
    float v = W[gid];
    ushort_t hi = f2bf(v);
    float r = v - bf2f(hi);
    Wh[p] = hi;
    Wl[p] = f2bf(r);
}

// ---------------------------------------------------------------------------
// MFMA GEMM, bf16x3 split precision: C[n,Mout](bf16) = A[n,256](f32) @ W
// 128x128 block tile, 4 waves (2x2), wave = 64x64, BK=32, K=256.
__global__ __launch_bounds__(256) void k_mm(const float* __restrict__ A,
                                            const ushort_t* __restrict__ Wh,
                                            const ushort_t* __restrict__ Wl,
                                            ushort_t* __restrict__ C, int n, int Mout) {
    __shared__ ushort_t Ah[128][40];   // +16B pad -> 2-way bank aliasing (free)
    __shared__ ushort_t Al[128][40];
    const int t = threadIdx.x;
    const int lane = t & 63, w = t >> 6;
    const int wr = w >> 1, wc = w & 1;
    const int r0 = blockIdx.x * 128;
    const int srow = t >> 1;             // staging row 0..127
    const int kh = (t & 1) * 16;         // staging k-offset 0 or 16
    const int arow = r0 + srow;
    const bool rowok = arow < n;

    f4v acc[4][4];
#pragma unroll
    for (int a = 0; a < 4; ++a)
#pragma unroll
        for (int b = 0; b < 4; ++b) { f4v z = {0.f, 0.f, 0.f, 0.f}; acc[a][b] = z; }

    float pre[16];
    const float* abase = &A[(size_t)arow * 256 + kh];
#pragma unroll
    for (int q = 0; q < 4; ++q) {
        float4 v = rowok ? *reinterpret_cast<const float4*>(abase + q * 4)
                         : float4{0.f, 0.f, 0.f, 0.f};
        pre[q * 4 + 0] = v.x; pre[q * 4 + 1] = v.y;
        pre[q * 4 + 2] = v.z; pre[q * 4 + 3] = v.w;
    }

    const int lj = lane & 15, lk = lane >> 4;

    for (int kb = 0; kb < 256; kb += 32) {
        __syncthreads();   // previous compute done reading LDS
        // convert staged f32 -> hi/lo bf16, write 16B chunks
#pragma unroll
        for (int q = 0; q < 2; ++q) {
            unsigned int hw[4], lw[4];
#pragma unroll
            for (int p = 0; p < 4; ++p) {
                float v0 = pre[q * 8 + p * 2], v1 = pre[q * 8 + p * 2 + 1];
                ushort_t h0 = f2bf(v0), h1 = f2bf(v1);
                ushort_t l0 = f2bf(v0 - bf2f(h0)), l1 = f2bf(v1 - bf2f(h1));
                hw[p] = (unsigned int)h0 | ((unsigned int)h1 << 16);
                lw[p] = (unsigned int)l0 | ((unsigned int)l1 << 16);
            }
            uint4 hv = {hw[0], hw[1], hw[2], hw[3]};
            uint4 lv = {lw[0], lw[1], lw[2], lw[3]};
            *reinterpret_cast<uint4*>(&Ah[srow][kh + q * 8]) = hv;
            *reinterpret_cast<uint4*>(&Al[srow][kh + q * 8]) = lv;
        }
        __syncthreads();
        // prefetch next A tile into regs (hides HBM latency under MFMA)
        if (kb < 224) {
            const float* ap = abase + kb + 32;
#pragma unroll
            for (int q = 0; q < 4; ++q) {
                float4 v = rowok ? *reinterpret_cast<const float4*>(ap + q * 4)
                                 : float4{0.f, 0.f, 0.f, 0.f};
                pre[q * 4 + 0] = v.x; pre[q * 4 + 1] = v.y;
                pre[q * 4 + 2] = v.z; pre[q * 4 + 3] = v.w;
            }
        }
        // compute: 48 MFMA per wave per K-step
        const int kc0 = kb >> 3;
        s8v ah[4], al[4];
#pragma unroll
        for (int mf = 0; mf < 4; ++mf) {
            const ushort_t* pa = &Ah[wr * 64 + mf * 16 + lj][lk * 8];
            const ushort_t* pl = &Al[wr * 64 + mf * 16 + lj][lk * 8];
            ah[mf] = *reinterpret_cast<const s8v*>(pa);
            al[mf] = *reinterpret_cast<const s8v*>(pl);
        }
#pragma unroll
        for (int nf = 0; nf < 4; ++nf) {
            int ntile = blockIdx.y * 8 + wc * 4 + nf;
            size_t boff = ((size_t)(ntile * 32 + kc0 + lk) * 16 + lj) * 8;
            s8v bh = *reinterpret_cast<const s8v*>(&Wh[boff]);
            s8v bl = *reinterpret_cast<const s8v*>(&Wl[boff]);
#pragma unroll
            for (int mf = 0; mf < 4; ++mf) {
                acc[mf][nf] = __builtin_amdgcn_mfma_f32_16x16x32_bf16(ah[mf], bh, acc[mf][nf], 0, 0, 0);
                acc[mf][nf] = __builtin_amdgcn_mfma_f32_16x16x32_bf16(ah[mf], bl, acc[mf][nf], 0, 0, 0);
                acc[mf][nf] = __builtin_amdgcn_mfma_f32_16x16x32_bf16(al[mf], bh, acc[mf][nf], 0, 0, 0);
            }
        }
    }

    // epilogue: D[i][j]: col = lane&15, row = (lane>>4)*4 + reg
#pragma unroll
    for (int mf = 0; mf < 4; ++mf) {
        int rr = r0 + wr * 64 + mf * 16 + lk * 4;
#pragma unroll
        for (int nf = 0; nf < 4; ++nf) {
            int cc = blockIdx.y * 128 + wc * 64 + nf * 16 + lj;
#pragma unroll
            for (int r = 0; r < 4; ++r) {
                if (rr + r < n) C[(size_t)(rr + r) * Mout + cc] = f2bf(acc[mf][nf][r]);
            }
        }
    }
}

// ---------------------------------------------------------------------------
// attention logit dot products
__global__ __launch_bounds__(256) void k_att1(const ushort_t* __restrict__ h1,
                                              const float* __restrict__ att_s,
                                              const float* __restrict__ att_d,
                                              float* __restrict__ as1,
                                              float* __restrict__ ad1, int n) {
    int wid = (blockIdx.x * blockDim.x + threadIdx.x) >> 6;
    int lane = threadIdx.x & 63;
    if (wid >= n) return;
    int head = lane >> 3;
    int co = (lane & 7) * 4;
    ushort4 hu = *reinterpret_cast<const ushort4*>(&h1[(size_t)wid * 256 + head * 32 + co]);
    float4 vs = *reinterpret_cast<const float4*>(&att_s[head * 32 + co]);
    float4 vd = *reinterpret_cast<const float4*>(&att_d[head * 32 + co]);
    float hx = bf2f(hu.x), hy = bf2f(hu.y), hz = bf2f(hu.z), hw = bf2f(hu.w);
    float ss = hx * vs.x + hy * vs.y + hz * vs.z + hw * vs.w;
    float sd = hx * vd.x + hy * vd.y + hz * vd.z + hw * vd.w;
#pragma unroll
    for (int o = 1; o < 8; o <<= 1) { ss += __shfl_xor(ss, o, 64); sd += __shfl_xor(sd, o, 64); }
    if ((lane & 7) == 0) {
        as1[(size_t)wid * 8 + head] = ss;
        ad1[(size_t)wid * 8 + head] = sd;
    }
}

__global__ __launch_bounds__(256) void k_att2(const ushort_t* __restrict__ h2,
                                              const float* __restrict__ att_s,
                                              const float* __restrict__ att_d,
                                              float* __restrict__ as2,
                                              float* __restrict__ ad2, int n) {
    int wid = (blockIdx.x * blockDim.x + threadIdx.x) >> 6;
    int lane = threadIdx.x & 63;
    if (wid >= n) return;
    ushort2 hu = *reinterpret_cast<const ushort2*>(&h2[(size_t)wid * 128 + lane * 2]);
    float2 vs = *reinterpret_cast<const float2*>(&att_s[lane * 2]);
    float2 vd = *reinterpret_cast<const float2*>(&att_d[lane * 2]);
    float hx = bf2f(hu.x), hy = bf2f(hu.y);
    float ss = hx * vs.x + hy * vs.y;
    float sd = hx * vd.x + hy * vd.y;
#pragma unroll
    for (int o = 1; o < 64; o <<= 1) { ss += __shfl_xor(ss, o, 64); sd += __shfl_xor(sd, o, 64); }
    if (lane == 0) { as2[wid] = ss; ad2[wid] = sd; }
}

// ---------------------------------------------------------------------------
// layer-1 aggregation: 1 wave/node, dual online-softmax accumulators
__global__ __launch_bounds__(256) void k_agg1(const ushort_t* __restrict__ h1,
                                              const float* __restrict__ as1,
                                              const float* __restrict__ ad1,
                                              const int* __restrict__ offs,
                                              const int* __restrict__ esrc,
                                              const float* __restrict__ b1,
                                              float* __restrict__ out1, int n) {
    int wid = (blockIdx.x * blockDim.x + threadIdx.x) >> 6;
    int lane = threadIdx.x & 63;
    if (wid >= n) return;
    int head = lane >> 3;
    int cb = lane * 4;
    float adn = ad1[(size_t)wid * 8 + head];
    int e0 = offs[wid], e1 = offs[wid + 1];
    float mA = -1e30f, dA = 0.f, axA = 0.f, ayA = 0.f, azA = 0.f, awA = 0.f;
    float mB = -1e30f, dB = 0.f, axB = 0.f, ayB = 0.f, azB = 0.f, awB = 0.f;
    int e = e0;
    for (; e + 1 < e1; e += 2) {
        int sA = esrc[e], sB = esrc[e + 1];
        float eaA = lrelu(as1[(size_t)sA * 8 + head] + adn);
        float eaB = lrelu(as1[(size_t)sB * 8 + head] + adn);
        ushort4 hA = *reinterpret_cast<const ushort4*>(&h1[(size_t)sA * 256 + cb]);
        ushort4 hB = *reinterpret_cast<const ushort4*>(&h1[(size_t)sB * 256 + cb]);
        float nmA = fmaxf(mA, eaA), nmB = fmaxf(mB, eaB);
        float scA = __expf(mA - nmA), scB = __expf(mB - nmB);
        float pA = __expf(eaA - nmA), pB = __expf(eaB - nmB);
        dA = dA * scA + pA;             dB = dB * scB + pB;
        axA = axA * scA + pA * bf2f(hA.x);  axB = axB * scB + pB * bf2f(hB.x);
        ayA = ayA * scA + pA * bf2f(hA.y);  ayB = ayB * scB + pB * bf2f(hB.y);
        azA = azA * scA + pA * bf2f(hA.z);  azB = azB * scB + pB * bf2f(hB.z);
        awA = awA * scA + pA * bf2f(hA.w);  awB = awB * scB + pB * bf2f(hB.w);
        mA = nmA; mB = nmB;
    }
    if (e < e1) {
        int s = esrc[e];
        float ea = lrelu(as1[(size_t)s * 8 + head] + adn);
        ushort4 hv = *reinterpret_cast<const ushort4*>(&h1[(size_t)s * 256 + cb]);
        float nm = fmaxf(mA, ea);
        float sc = __expf(mA - nm), p = __expf(ea - nm);
        dA = dA * sc + p;
        axA = axA * sc + p * bf2f(hv.x);
        ayA = ayA * sc + p * bf2f(hv.y);
        azA = azA * sc + p * bf2f(hv.z);
        awA = awA * sc + p * bf2f(hv.w);
        mA = nm;
    }
    {
        float nm = fmaxf(mA, mB);
        float scA = __expf(mA - nm), scB = __expf(mB - nm);
        dA = dA * scA + dB * scB;
        axA = axA * scA + axB * scB;
        ayA = ayA * scA + ayB * scB;
        azA = azA * scA + azB * scB;
        awA = awA * scA + awB * scB;
    }
    float inv = 1.f / (dA + 1e-16f);
    float4 bb = *reinterpret_cast<const float4*>(&b1[cb]);
    float4 o;
    o.x = fmaxf(axA * inv + bb.x, 0.f);
    o.y = fmaxf(ayA * inv + bb.y, 0.f);
    o.z = fmaxf(azA * inv + bb.z, 0.f);
    o.w = fmaxf(awA * inv + bb.w, 0.f);
    *reinterpret_cast<float4*>(&out1[(size_t)wid * 256 + cb]) = o;
}

// layer-2 aggregation
__global__ __launch_bounds__(256) void k_agg2(const ushort_t* __restrict__ h2,
                                              const float* __restrict__ as2,
                                              const float* __restrict__ ad2,
                                              const int* __restrict__ offs,
                                              const int* __restrict__ esrc,
                                              const float* __restrict__ b2,
                                              float* __restrict__ out2, int n) {
    int wid = (blockIdx.x * blockDim.x + threadIdx.x) >> 6;
    int lane = threadIdx.x & 63;
    if (wid >= n) return;
    int cb = lane * 2;
    float adn = ad2[wid];
    int e0 = offs[wid], e1 = offs[wid + 1];
    float mA = -1e30f, dA = 0.f, axA = 0.f, ayA = 0.f;
    float mB = -1e30f, dB = 0.f, axB = 0.f, ayB = 0.f;
    int e = e0;
    for (; e + 1 < e1; e += 2) {
        int sA = esrc[e], sB = esrc[e + 1];
        float eaA = lrelu(as2[sA] + adn);
        float eaB = lrelu(as2[sB] + adn);
        ushort2 hA = *reinterpret_cast<const ushort2*>(&h2[(size_t)sA * 128 + cb]);
        ushort2 hB = *reinterpret_cast<const ushort2*>(&h2[(size_t)sB * 128 + cb]);
        float nmA = fmaxf(mA, eaA), nmB = fmaxf(mB, eaB);
        float scA = __expf(mA - nmA), scB = __expf(mB - nmB);
        float pA = __expf(eaA - nmA), pB = __expf(eaB - nmB);
        dA = dA * scA + pA;                 dB = dB * scB + pB;
        axA = axA * scA + pA * bf2f(hA.x); axB = axB * scB + pB * bf2f(hB.x);
        ayA = ayA * scA + pA * bf2f(hA.y); ayB = ayB * scB + pB * bf2f(hB.y);
        mA = nmA; mB = nmB;
    }
    if (e < e1) {
        int s = esrc[e];
        float ea = lrelu(as2[s] + adn);
        ushort2 hv = *reinterpret_cast<const ushort2*>(&h2[(size_t)s * 128 + cb]);
        float nm = fmaxf(mA, ea);
        float sc = __expf(mA - nm), p = __expf(ea - nm);
        dA = dA * sc + p;
        axA = axA * sc + p * bf2f(hv.x);
        ayA = ayA * sc + p * bf2f(hv.y);
        mA = nm;
    }
    {
        float nm = fmaxf(mA, mB);
        float scA = __expf(mA - nm), scB = __expf(mB - nm);
        dA = dA * scA + dB * scB;
        axA = axA * scA + axB * scB;
        ayA = ayA * scA + ayB * scB;
    }
    float inv = 1.f / (dA + 1e-16f);
    float o0 = fmaxf(axA * inv + b2[cb], 0.f);
    float o1 = fmaxf(ayA * inv + b2[cb + 1], 0.f);
    float2 o = {o0, o1};
    *reinterpret_cast<float2*>(&out2[(size_t)wid * 128 + cb]) = o;
}

// ---------------------------------------------------------------------------
__global__ __launch_bounds__(128) void k_bnstat(const float* __restrict__ out2,
                                                float* __restrict__ bnsum,
                                                float* __restrict__ bnsq, int n) {
    int c = threadIdx.x;
    float s = 0.f, q = 0.f;
    for (int r = blockIdx.x; r < n; r += gridDim.x) {
        float v = out2[(size_t)r * 128 + c];
        s += v;
        q += v * v;
    }
    atomicAdd(&bnsum[c], s);
    atomicAdd(&bnsq[c], q);
}

__global__ __launch_bounds__(256) void k_final(const float* __restrict__ out2,
                                               const float* __restrict__ bnsum,
                                               const float* __restrict__ bnsq,
                                               const float* __restrict__ bng,
                                               const float* __restrict__ bnb,
                                               const float* __restrict__ lng,
                                               const float* __restrict__ lnb,
                                               float* __restrict__ out, int n) {
    int wid = (blockIdx.x * blockDim.x + threadIdx.x) >> 6;
    int lane = threadIdx.x & 63;
    if (wid >= n) return;
    int c0 = lane, c1 = lane + 64;
    float invn = 1.f / (float)n;
    float mu0 = bnsum[c0] * invn, mu1 = bnsum[c1] * invn;
    float v0 = bnsq[c0] * invn - mu0 * mu0;
    float v1 = bnsq[c1] * invn - mu1 * mu1;
    float r0 = rsqrtf(v0 + EPSV), r1 = rsqrtf(v1 + EPSV);
    float x0 = out2[(size_t)wid * 128 + c0];
    float x1 = out2[(size_t)wid * 128 + c1];
    float y0 = (x0 - mu0) * r0 * bng[c0] + bnb[c0];
    float y1 = (x1 - mu1) * r1 * bng[c1] + bnb[c1];
    float s = y0 + y1, q = y0 * y0 + y1 * y1;
#pragma unroll
    for (int o = 1; o < 64; o <<= 1) { s += __shfl_xor(s, o, 64); q += __shfl_xor(q, o, 64); }
    float mu = s * (1.f / 128.f);
    float var = q * (1.f / 128.f) - mu * mu;
    float rr = rsqrtf(var + EPSV);
    out[(size_t)wid * 128 + c0] = (y0 - mu) * rr * lng[c0] + lnb[c0];
    out[(size_t)wid * 128 + c1] = (y1 - mu) * rr * lng[c1] + lnb[c1];
}

// ---------------------------------------------------------------------------
extern "C" void kernel_launch(void* const* d_in, const int* in_sizes, int n_in,
                              void* d_out, int out_size, void* d_ws, size_t ws_size,
                              hipStream_t stream) {
    const float* x    = (const float*)d_in[0];
    const int*   ei   = (const int*)d_in[1];
    const float* W1   = (const float*)d_in[2];
    const float* ats1 = (const float*)d_in[3];
    const float* atd1 = (const float*)d_in[4];
    const float* b1   = (const float*)d_in[5];
    const float* W2   = (const float*)d_in[6];
    const float* ats2 = (const float*)d_in[7];
    const float* atd2 = (const float*)d_in[8];
    const float* b2   = (const float*)d_in[9];
    const float* bng  = (const float*)d_in[10];
    const float* bnb  = (const float*)d_in[11];
    const float* lng  = (const float*)d_in[12];
    const float* lnb  = (const float*)d_in[13];

    const int n = in_sizes[0] / NFEAT;   // 50000
    const int E = in_sizes[1] / 2;       // 800000
    const int tot = E + n;

    auto align = [](size_t v) { return (v + 255) & ~(size_t)255; };
    char* ws = (char*)d_ws;
    size_t off = 0;
    ushort_t* h1 = (ushort_t*)(ws + off); off += align((size_t)n * 256 * 2);
    float* out1 = (float*)(ws + off); off += align((size_t)n * 256 * 4);
    ushort_t* h2 = h1;
    float* out2 = out1;
    float* as1 = (float*)(ws + off); off += align((size_t)n * 8 * 4);
    float* ad1 = (float*)(ws + off); off += align((size_t)n * 8 * 4);
    float* as2 = (float*)(ws + off); off += align((size_t)n * 4);
    float* ad2 = (float*)(ws + off); off += align((size_t)n * 4);
    int* counts = (int*)(ws + off); off += align((size_t)n * 4);
    int* offs   = (int*)(ws + off); off += align((size_t)(n + 1) * 4);
    int* cursor = (int*)(ws + off); off += align((size_t)n * 4);
    int* esrc   = (int*)(ws + off); off += align((size_t)tot * 4);
    int* incl   = (int*)(ws + off); off += align((size_t)n * 4);
    int* bsum   = (int*)(ws + off); off += align(64 * 4);
    int* flag   = (int*)(ws + off); off += align(4);
    float* bnsum = (float*)(ws + off); off += align(128 * 4);
    float* bnsq  = (float*)(ws + off); off += align(128 * 4);
    ushort_t* Wh1 = (ushort_t*)(ws + off); off += align((size_t)256 * 256 * 2);
    ushort_t* Wl1 = (ushort_t*)(ws + off); off += align((size_t)256 * 256 * 2);
    ushort_t* Wh2 = (ushort_t*)(ws + off); off += align((size_t)256 * 128 * 2);
    ushort_t* Wl2 = (ushort_t*)(ws + off); off += align((size_t)256 * 128 * 2);

    hipMemsetAsync(counts, 0, (size_t)n * 4, stream);
    hipMemsetAsync(bnsum, 0, 128 * 4, stream);
    hipMemsetAsync(bnsq, 0, 128 * 4, stream);

    // W packing (runs while CSR builds; tiny)
    k_prepw<<<(256 * 256 + 255) / 256, 256, 0, stream>>>(W1, Wh1, Wl1, 256, 256);
    k_prepw<<<(256 * 128 + 255) / 256, 256, 0, stream>>>(W2, Wh2, Wl2, 256, 128);

    // edge dtype detection + CSR build
    k_detect<<<1, 64, 0, stream>>>(ei, E, flag);
    k_count<<<(tot + 255) / 256, 256, 0, stream>>>(ei, flag, counts, E, n);
    int nsb = (n + 1023) / 1024;
    k_scan1<<<nsb, 1024, 0, stream>>>(counts, incl, bsum, n);
    k_scan2<<<1, 64, 0, stream>>>(bsum, nsb);
    k_scan3<<<(n + 255) / 256, 256, 0, stream>>>(incl, bsum, counts, offs, cursor, n);
    k_fill<<<(tot + 255) / 256, 256, 0, stream>>>(ei, flag, cursor, esrc, E, n);

    const int gx = (n + 127) / 128;
    // layer 1
    k_mm<<<dim3(gx, 2), 256, 0, stream>>>(x, Wh1, Wl1, h1, n, 256);
    k_att1<<<(n + 3) / 4, 256, 0, stream>>>(h1, ats1, atd1, as1, ad1, n);
    k_agg1<<<(n + 3) / 4, 256, 0, stream>>>(h1, as1, ad1, offs, esrc, b1, out1, n);

    // layer 2
    k_mm<<<dim3(gx, 1), 256, 0, stream>>>(out1, Wh2, Wl2, h2, n, 128);
    k_att2<<<(n + 3) / 4, 256, 0, stream>>>(h2, ats2, atd2, as2, ad2, n);
    k_agg2<<<(n + 3) / 4, 256, 0, stream>>>(h2, as2, ad2, offs, esrc, b2, out2, n);

    // BN + LN
    k_bnstat<<<512, 128, 0, stream>>>(out2, bnsum, bnsq, n);
    k_final<<<(n + 3) / 4, 256, 0, stream>>>(out2, bnsum, bnsq, bng, bnb, lng, lnb,
                                             (float*)d_out, n);
}